// Round 13
// baseline (465.726 us; speedup 1.0000x reference)
//
#include <hip/hip_runtime.h>
#include <hip/hip_bf16.h>
#include <hip/hip_fp16.h>

#define F 256
#define KC 1024           // concatenated K = R * F
#define BM 128
#define BN 128
#define BK 32
#define NT (KC / BK)      // 32 K-steps
#define SCAN_T 256
#define SCAN_ELEMS 1024
#define BCAP 5120         // staging capacity per bucket
#define ACHUNK 4096       // edges per bucket_a block

typedef __attribute__((ext_vector_type(8))) short bf16x8;
typedef __attribute__((ext_vector_type(4))) float f32x4;
typedef __attribute__((address_space(3))) unsigned int* lds_u32p;
typedef const __attribute__((address_space(1))) unsigned int* glb_u32p;

__device__ __forceinline__ float bf2f(unsigned short u) {
    return __uint_as_float((unsigned)u << 16);
}
__device__ __forceinline__ unsigned short f2bf(float x) {
    return __bfloat16_as_ushort(__float2bfloat16(x));
}
// epack entry: low 16 = src (N < 65536), high 16 = val as fp16
__device__ __forceinline__ float ep_val(unsigned p) {
    return __half2float(__ushort_as_half((unsigned short)(p >> 16)));
}

// ---------------- convert fp32 [N][256] -> bf16 [N][256] ----------------
__global__ __launch_bounds__(256) void convert_bf16(const float* __restrict__ in,
                                                    unsigned short* __restrict__ outb,
                                                    int total8) {
    int i = blockIdx.x * 256 + threadIdx.x;
    if (i >= total8) return;
    const float* p = in + (size_t)i * 8;
    float4 a = *(const float4*)p;
    float4 b = *(const float4*)(p + 4);
    bf16x8 v;
    v[0] = f2bf(a.x); v[1] = f2bf(a.y); v[2] = f2bf(a.z); v[3] = f2bf(a.w);
    v[4] = f2bf(b.x); v[5] = f2bf(b.y); v[6] = f2bf(b.z); v[7] = f2bf(b.w);
    *(bf16x8*)(outb + (size_t)i * 8) = v;
}

// ---- W [R][256(k)][256(c)] fp32 -> WT [256(c)][1024(r*256+k)] bf16 ----
__global__ __launch_bounds__(256) void transpose_wcat2(const float* __restrict__ W1,
                                                       const float* __restrict__ W2,
                                                       unsigned short* __restrict__ WT1,
                                                       unsigned short* __restrict__ WT2,
                                                       int R) {
    __shared__ float t[32][33];
    const int z = blockIdx.z;
    const int rel = z % R;
    const float* Wr = (z < R ? W1 : W2) + (size_t)rel * F * F;
    unsigned short* WT = (z < R ? WT1 : WT2);
    const int k0 = blockIdx.x * 32, c0 = blockIdx.y * 32;
    const int tx = threadIdx.x & 31, ty = threadIdx.x >> 5;
#pragma unroll
    for (int i = 0; i < 32; i += 8)
        t[ty + i][tx] = Wr[(size_t)(k0 + ty + i) * F + c0 + tx];
    __syncthreads();
#pragma unroll
    for (int i = 0; i < 32; i += 8)
        WT[(size_t)(c0 + ty + i) * KC + rel * F + k0 + tx] = f2bf(t[tx][ty + i]);
}

// ---------------- CSR build: bucketed two-pass ----------------
__global__ __launch_bounds__(512) void bucket_a(const int* __restrict__ esrc,
                                                const int* __restrict__ edst,
                                                const float* __restrict__ eval,
                                                int* __restrict__ counts,
                                                int* __restrict__ gcursor,
                                                uint2* __restrict__ staging,
                                                int total, int E, int Nn, int nbkt) {
    __shared__ int cnt[512];
    __shared__ int base[512];
    const int t = threadIdx.x;
    if (t < nbkt) cnt[t] = 0;
    __syncthreads();

    const int i0 = blockIdx.x * ACHUNK;
    int bkt[8], lrank[8], key[8];
    unsigned pk[8], w2[8];
#pragma unroll
    for (int j = 0; j < 8; ++j) {
        const int i = i0 + j * 512 + t;
        if (i < total) {
            const int r = i / E;
            const int d = edst[i];
            const unsigned short vb = __half_as_ushort(__float2half_rn(eval[i]));
            pk[j] = (unsigned)(esrc[i] & 0xffff) | ((unsigned)vb << 16);
            key[j] = r * Nn + d;
            const int lk = r * 128 + (d & 127);
            w2[j] = (unsigned)key[j] | ((unsigned)lk << 18);
            bkt[j] = d >> 7;
            lrank[j] = atomicAdd(&cnt[bkt[j]], 1);
            atomicAdd(counts + key[j], 1);
        } else {
            bkt[j] = -1;
        }
    }
    __syncthreads();
    if (t < nbkt) {
        base[t] = (cnt[t] > 0) ? atomicAdd(&gcursor[t], cnt[t]) : 0;
    }
    __syncthreads();
#pragma unroll
    for (int j = 0; j < 8; ++j) {
        if (bkt[j] >= 0) {
            staging[(size_t)bkt[j] * BCAP + base[bkt[j]] + lrank[j]] =
                make_uint2(pk[j], w2[j]);
        }
    }
}

__global__ __launch_bounds__(256) void bucket_b(const uint2* __restrict__ staging,
                                                const int* __restrict__ gcursor,
                                                const int* __restrict__ row_ptr,
                                                unsigned* __restrict__ epack) {
    __shared__ int cnt2[512];
    const int b = blockIdx.x;
    const int t = threadIdx.x;
    cnt2[t] = 0;
    cnt2[t + 256] = 0;
    __syncthreads();
    const int cb = gcursor[b];
    for (int i = t; i < cb; i += 256) {
        const uint2 en = staging[(size_t)b * BCAP + i];
        const int key = (int)(en.y & 0x3ffff);
        const int lk = (int)(en.y >> 18);
        const int rank = atomicAdd(&cnt2[lk], 1);
        epack[row_ptr[key] + rank] = en.x;
    }
}

// ---------------- scans for row_ptr ----------------
__global__ __launch_bounds__(SCAN_T) void scan1_kern(int* __restrict__ data,
                                                     int* __restrict__ bsum, int n) {
    __shared__ int sh[SCAN_T];
    const int t = threadIdx.x;
    const int base = blockIdx.x * SCAN_ELEMS + t * 4;
    int v[4];
    int tsum = 0;
#pragma unroll
    for (int j = 0; j < 4; ++j) {
        v[j] = (base + j < n) ? data[base + j] : 0;
        tsum += v[j];
    }
    sh[t] = tsum;
    __syncthreads();
    for (int off = 1; off < SCAN_T; off <<= 1) {
        int x = (t >= off) ? sh[t - off] : 0;
        __syncthreads();
        sh[t] += x;
        __syncthreads();
    }
    if (t == SCAN_T - 1) bsum[blockIdx.x] = sh[t];
    int run = sh[t] - tsum;
#pragma unroll
    for (int j = 0; j < 4; ++j) {
        if (base + j < n) data[base + j] = run;
        run += v[j];
    }
}

__global__ __launch_bounds__(SCAN_T) void scan2_kern(int* __restrict__ bsum, int nb) {
    __shared__ int sh[SCAN_T];
    const int t = threadIdx.x;
    int val = (t < nb) ? bsum[t] : 0;
    sh[t] = val;
    __syncthreads();
    for (int off = 1; off < SCAN_T; off <<= 1) {
        int x = (t >= off) ? sh[t - off] : 0;
        __syncthreads();
        sh[t] += x;
        __syncthreads();
    }
    if (t < nb) bsum[t] = sh[t] - val;
}

__global__ __launch_bounds__(256) void scan3_kern(int* __restrict__ row_ptr,
                                                  const int* __restrict__ bsum,
                                                  int n, int total) {
    int i = blockIdx.x * blockDim.x + threadIdx.x;
    if (i < n) {
        row_ptr[i] = row_ptr[i] + bsum[i >> 10];
    } else if (i == n) {
        row_ptr[n] = total;
    }
}

// ---------------- Gather-aggregate: 2 edges per wave, 16 B/lane ----------------
__global__ __launch_bounds__(256) void aggregate_g(const unsigned short* __restrict__ xb,
                                                   const int* __restrict__ row_ptr,
                                                   const unsigned* __restrict__ epack,
                                                   unsigned short* __restrict__ Y,
                                                   int Nn) {
    const int d = blockIdx.x;
    const int r = threadIdx.x >> 6;
    if (d >= Nn) return;
    const int lane = threadIdx.x & 63;
    const int half = lane >> 5;
    const int f8 = (lane & 31) * 8;

    const int key = r * Nn + d;
    int e = row_ptr[key];
    const int end = row_ptr[key + 1];

    float acc[8] = {0.f, 0.f, 0.f, 0.f, 0.f, 0.f, 0.f, 0.f};

    for (; e + 8 <= end; e += 8) {
        unsigned p0 = epack[e + 0 + half];
        unsigned p1 = epack[e + 2 + half];
        unsigned p2 = epack[e + 4 + half];
        unsigned p3 = epack[e + 6 + half];
        bf16x8 h0 = *(const bf16x8*)(xb + (size_t)(p0 & 0xffff) * F + f8);
        bf16x8 h1 = *(const bf16x8*)(xb + (size_t)(p1 & 0xffff) * F + f8);
        bf16x8 h2 = *(const bf16x8*)(xb + (size_t)(p2 & 0xffff) * F + f8);
        bf16x8 h3 = *(const bf16x8*)(xb + (size_t)(p3 & 0xffff) * F + f8);
        const float v0 = ep_val(p0), v1 = ep_val(p1);
        const float v2 = ep_val(p2), v3 = ep_val(p3);
#pragma unroll
        for (int j = 0; j < 8; ++j) acc[j] = fmaf(bf2f((unsigned short)h0[j]), v0, acc[j]);
#pragma unroll
        for (int j = 0; j < 8; ++j) acc[j] = fmaf(bf2f((unsigned short)h1[j]), v1, acc[j]);
#pragma unroll
        for (int j = 0; j < 8; ++j) acc[j] = fmaf(bf2f((unsigned short)h2[j]), v2, acc[j]);
#pragma unroll
        for (int j = 0; j < 8; ++j) acc[j] = fmaf(bf2f((unsigned short)h3[j]), v3, acc[j]);
    }
    for (; e + 2 <= end; e += 2) {
        unsigned p = epack[e + half];
        const float v = ep_val(p);
        bf16x8 h = *(const bf16x8*)(xb + (size_t)(p & 0xffff) * F + f8);
#pragma unroll
        for (int j = 0; j < 8; ++j) acc[j] = fmaf(bf2f((unsigned short)h[j]), v, acc[j]);
    }
    if (e < end) {
        unsigned p = epack[e];
        const float v = half == 0 ? ep_val(p) : 0.f;
        bf16x8 h = *(const bf16x8*)(xb + (size_t)(p & 0xffff) * F + f8);
#pragma unroll
        for (int j = 0; j < 8; ++j) acc[j] = fmaf(bf2f((unsigned short)h[j]), v, acc[j]);
    }

#pragma unroll
    for (int j = 0; j < 8; ++j) acc[j] += __shfl_xor(acc[j], 32);

    if (half == 0) {
        bf16x8 o;
#pragma unroll
        for (int j = 0; j < 8; ++j) o[j] = (short)f2bf(acc[j]);
        *(bf16x8*)(Y + (size_t)d * KC + r * F + f8) = o;
    }
}

// ---------------- LDS-staged MFMA GEMM, BM=128 BN=128, 2-phase dbuf ------------
// C = Y[Mp,1024] @ WT^T;  512 thr, 8 waves (2x4), per-wave 64x32 output.
// LAYER1: x1b = bf16(relu(C+b)) ONLY (no fp32 out write).
// LAYER2: out = relu(C+b) + bf2f(x1b)   (bf16 skip path)
template <bool LAYER2>
__global__ __launch_bounds__(512) void gemm_fused(const unsigned short* __restrict__ A,
                                                  const unsigned short* __restrict__ WT,
                                                  const float* __restrict__ bias,
                                                  float* __restrict__ out,
                                                  unsigned short* __restrict__ x1b,
                                                  int Nn, int nwg) {
    __shared__ unsigned short As[2][BM][BK];   // 2 x 8 KB
    __shared__ unsigned short Bs[2][BN][BK];   // 2 x 8 KB

    // bijective XCD swizzle (m204); consecutive swz share an A row-panel
    const int xcd = blockIdx.x % 8;
    const int j = blockIdx.x / 8;
    const int q = nwg / 8, rr = nwg % 8;
    const int swz = (xcd < rr ? xcd * (q + 1) : rr * (q + 1) + (xcd - rr) * q) + j;
    const int rb = swz >> 1;
    const int cb = swz & 1;
    const int row0 = rb * BM;
    const int col0 = cb * BN;

    const int tid = threadIdx.x;
    const int wave = tid >> 6, lane = tid & 63;
    const int wr = wave >> 2, wc = wave & 3;     // 2 x 4 wave grid, 64x32 each

    const int lrow = lane & 15, lk8 = (lane >> 4) * 8;

    const int srow = tid >> 2;          // 0..127
    const int scol = (tid & 3) * 8;

    f32x4 acc[4][2] = {};

#define STAGE(buf, k0)                                                               \
    {                                                                                \
        const unsigned short* gA = A + (size_t)(row0 + srow) * KC + (k0) + scol;     \
        __builtin_amdgcn_global_load_lds((glb_u32p)gA,                               \
            (lds_u32p)&As[buf][wave * 16][0], 16, 0, 0);                             \
        const unsigned short* gB = WT + (size_t)(col0 + srow) * KC + (k0) + scol;    \
        __builtin_amdgcn_global_load_lds((glb_u32p)gB,                               \
            (lds_u32p)&Bs[buf][wave * 16][0], 16, 0, 0);                             \
    }

#define COMPUTE(buf)                                                                 \
    {                                                                                \
        bf16x8 a[4], b[2];                                                           \
        _Pragma("unroll")                                                            \
        for (int m = 0; m < 4; ++m)                                                  \
            a[m] = *(const bf16x8*)&As[buf][wr * 64 + m * 16 + lrow][lk8];           \
        _Pragma("unroll")                                                            \
        for (int n = 0; n < 2; ++n)                                                  \
            b[n] = *(const bf16x8*)&Bs[buf][wc * 32 + n * 16 + lrow][lk8];           \
        _Pragma("unroll")                                                            \
        for (int m = 0; m < 4; ++m)                                                  \
            _Pragma("unroll")                                                        \
            for (int n = 0; n < 2; ++n)                                              \
                acc[m][n] = __builtin_amdgcn_mfma_f32_16x16x32_bf16(a[m], b[n],      \
                                                                   acc[m][n], 0, 0, 0); \
    }

    STAGE(0, 0)
    __syncthreads();
    int cur = 0;
#pragma unroll 2
    for (int t = 0; t < NT - 1; ++t) {
        STAGE(cur ^ 1, (t + 1) * BK)
        COMPUTE(cur)
        __syncthreads();
        cur ^= 1;
    }
    COMPUTE(cur)
#undef STAGE
#undef COMPUTE

    // C/D layout: col = lane&15, row = (lane>>4)*4 + q  [m89/m91]
    const int crow = (lane >> 4) * 4;
    const int ccol = lane & 15;
#pragma unroll
    for (int m = 0; m < 4; ++m) {
#pragma unroll
        for (int q4 = 0; q4 < 4; ++q4) {
            const int grow = row0 + wr * 64 + m * 16 + crow + q4;
            if (grow >= Nn) continue;
#pragma unroll
            for (int n = 0; n < 2; ++n) {
                const int gcol = col0 + wc * 32 + n * 16 + ccol;
                float v = acc[m][n][q4] + bias[gcol];
                v = fmaxf(v, 0.f);
                const size_t oi = (size_t)grow * F + gcol;
                if (LAYER2) {
                    out[oi] = v + bf2f(x1b[oi]);   // bf16 skip path
                } else {
                    x1b[oi] = f2bf(v);             // x1 stored bf16 only
                }
            }
        }
    }
}

extern "C" void kernel_launch(void* const* d_in, const int* in_sizes, int n_in,
                              void* d_out, int out_size, void* d_ws, size_t ws_size,
                              hipStream_t stream) {
    const float* x    = (const float*)d_in[0];
    const int*   esrc = (const int*)  d_in[1];
    const int*   edst = (const int*)  d_in[2];
    const float* eval = (const float*)d_in[3];
    const float* W1   = (const float*)d_in[4];
    const float* b1   = (const float*)d_in[5];
    const float* W2   = (const float*)d_in[6];
    const float* b2   = (const float*)d_in[7];
    float* out = (float*)d_out;

    const int N = in_sizes[0] / F;
    const int R = in_sizes[4] / (F * F);
    const int E = in_sizes[1] / R;
    const int RE = R * E;
    const int RN = R * N;
    const int nrb = (N + BM - 1) / BM;         // 391 for N=50000
    const int Mp = nrb * BM;
    const int nwg = nrb * 2;                   // BN=128 -> 2 col blocks
    const int nbkt = (N + 127) >> 7;           // 391 dst-buckets

    // ---- workspace layout ----
    char* ws = (char*)d_ws;
    unsigned short* Y = (unsigned short*)ws;             // [Mp][1024] bf16
    ws += (size_t)Mp * KC * sizeof(unsigned short);
    unsigned short* xb = (unsigned short*)ws;            // [N][256] bf16
    ws += (size_t)N * F * sizeof(unsigned short);
    unsigned short* x1b = (unsigned short*)ws;           // [N][256] bf16
    ws += (size_t)N * F * sizeof(unsigned short);
    unsigned short* WTc1 = (unsigned short*)ws;          // [256][1024] bf16
    ws += (size_t)F * KC * sizeof(unsigned short);
    unsigned short* WTc2 = (unsigned short*)ws;
    ws += (size_t)F * KC * sizeof(unsigned short);
    unsigned* epack = (unsigned*)ws;                     // [R*E] 4B packed
    ws += (size_t)RE * sizeof(unsigned);
    int* row_ptr = (int*)ws;                             // [R*N + 1]
    ws += (size_t)(RN + 1) * sizeof(int);
    int* gcursor = (int*)ws;                             // [nbkt]
    ws += (size_t)nbkt * sizeof(int);
    int* bsum = (int*)ws;                                // [<=256]
    ws += 256 * sizeof(int);
    uint2* staging = (uint2*)ws;                         // [nbkt*BCAP]
    ws += (size_t)nbkt * BCAP * sizeof(uint2);

    // ---- CSR build ----
    hipMemsetAsync(row_ptr, 0, ((size_t)(RN + 1) + nbkt) * sizeof(int), stream);
    {
        const int ablocks = (RE + ACHUNK - 1) / ACHUNK;
        bucket_a<<<ablocks, 512, 0, stream>>>(esrc, edst, eval, row_ptr, gcursor,
                                              staging, RE, E, N, nbkt);
    }
    const int nb_scan = (RN + SCAN_ELEMS - 1) / SCAN_ELEMS;
    scan1_kern<<<nb_scan, SCAN_T, 0, stream>>>(row_ptr, bsum, RN);
    scan2_kern<<<1, SCAN_T, 0, stream>>>(bsum, nb_scan);
    scan3_kern<<<(RN + 1 + 255) / 256, 256, 0, stream>>>(row_ptr, bsum, RN, RE);
    bucket_b<<<nbkt, 256, 0, stream>>>(staging, gcursor, row_ptr, epack);

    // ---- weight transpose+convert ----
    dim3 tgrid(F / 32, F / 32, 2 * R);
    transpose_wcat2<<<tgrid, 256, 0, stream>>>(W1, W2, WTc1, WTc2, R);

    // ---- input conversion ----
    convert_bf16<<<(N * (F / 8) + 255) / 256, 256, 0, stream>>>(x, xb, N * (F / 8));

    // layer 1: Y = gather(xb); x1b = bf16(relu(Y @ Wc1 + b1))
    aggregate_g<<<N, 256, 0, stream>>>(xb, row_ptr, epack, Y, N);
    gemm_fused<false><<<nwg, 512, 0, stream>>>(Y, WTc1, b1, out, x1b, N, nwg);

    // layer 2: Y = gather(x1b); out = relu(Y @ Wc2 + b2) + x1b
    aggregate_g<<<N, 256, 0, stream>>>(x1b, row_ptr, epack, Y, N);
    gemm_fused<true><<<nwg, 512, 0, stream>>>(Y, WTc2, b2, out, x1b, N, nwg);
}

// Round 14
// 441.210 us; speedup vs baseline: 1.0556x; 1.0556x over previous
//
#include <hip/hip_runtime.h>
#include <hip/hip_bf16.h>
#include <hip/hip_fp16.h>

#define F 256
#define KC 1024           // concatenated K = R * F
#define BM 128
#define BN 256
#define BK 32
#define NT (KC / BK)      // 32 K-steps
#define SCAN_T 256
#define SCAN_ELEMS 1024
#define BCAP 5120         // staging capacity per bucket
#define ACHUNK 4096       // edges per bucket_a block

typedef __attribute__((ext_vector_type(8))) short bf16x8;
typedef __attribute__((ext_vector_type(4))) float f32x4;
typedef __attribute__((address_space(3))) unsigned int* lds_u32p;
typedef const __attribute__((address_space(1))) unsigned int* glb_u32p;

__device__ __forceinline__ float bf2f(unsigned short u) {
    return __uint_as_float((unsigned)u << 16);
}
__device__ __forceinline__ unsigned short f2bf(float x) {
    return __bfloat16_as_ushort(__float2bfloat16(x));
}
// epack entry: low 16 = src (N < 65536), high 16 = val as fp16
__device__ __forceinline__ float ep_val(unsigned p) {
    return __half2float(__ushort_as_half((unsigned short)(p >> 16)));
}

// ---------------- convert fp32 [N][256] -> bf16 [N][256] ----------------
__global__ __launch_bounds__(256) void convert_bf16(const float* __restrict__ in,
                                                    unsigned short* __restrict__ outb,
                                                    int total8) {
    int i = blockIdx.x * 256 + threadIdx.x;
    if (i >= total8) return;
    const float* p = in + (size_t)i * 8;
    float4 a = *(const float4*)p;
    float4 b = *(const float4*)(p + 4);
    bf16x8 v;
    v[0] = f2bf(a.x); v[1] = f2bf(a.y); v[2] = f2bf(a.z); v[3] = f2bf(a.w);
    v[4] = f2bf(b.x); v[5] = f2bf(b.y); v[6] = f2bf(b.z); v[7] = f2bf(b.w);
    *(bf16x8*)(outb + (size_t)i * 8) = v;
}

// ---- W [R][256(k)][256(c)] fp32 -> WT [256(c)][1024(r*256+k)] bf16 ----
__global__ __launch_bounds__(256) void transpose_wcat2(const float* __restrict__ W1,
                                                       const float* __restrict__ W2,
                                                       unsigned short* __restrict__ WT1,
                                                       unsigned short* __restrict__ WT2,
                                                       int R) {
    __shared__ float t[32][33];
    const int z = blockIdx.z;
    const int rel = z % R;
    const float* Wr = (z < R ? W1 : W2) + (size_t)rel * F * F;
    unsigned short* WT = (z < R ? WT1 : WT2);
    const int k0 = blockIdx.x * 32, c0 = blockIdx.y * 32;
    const int tx = threadIdx.x & 31, ty = threadIdx.x >> 5;
#pragma unroll
    for (int i = 0; i < 32; i += 8)
        t[ty + i][tx] = Wr[(size_t)(k0 + ty + i) * F + c0 + tx];
    __syncthreads();
#pragma unroll
    for (int i = 0; i < 32; i += 8)
        WT[(size_t)(c0 + ty + i) * KC + rel * F + k0 + tx] = f2bf(t[tx][ty + i]);
}

// ---------------- CSR build: bucketed two-pass ----------------
__global__ __launch_bounds__(512) void bucket_a(const int* __restrict__ esrc,
                                                const int* __restrict__ edst,
                                                const float* __restrict__ eval,
                                                int* __restrict__ counts,
                                                int* __restrict__ gcursor,
                                                uint2* __restrict__ staging,
                                                int total, int E, int Nn, int nbkt) {
    __shared__ int cnt[512];
    __shared__ int base[512];
    const int t = threadIdx.x;
    if (t < nbkt) cnt[t] = 0;
    __syncthreads();

    const int i0 = blockIdx.x * ACHUNK;
    int bkt[8], lrank[8], key[8];
    unsigned pk[8], w2[8];
#pragma unroll
    for (int j = 0; j < 8; ++j) {
        const int i = i0 + j * 512 + t;
        if (i < total) {
            const int r = i / E;
            const int d = edst[i];
            const unsigned short vb = __half_as_ushort(__float2half_rn(eval[i]));
            pk[j] = (unsigned)(esrc[i] & 0xffff) | ((unsigned)vb << 16);
            key[j] = r * Nn + d;
            const int lk = r * 128 + (d & 127);
            w2[j] = (unsigned)key[j] | ((unsigned)lk << 18);
            bkt[j] = d >> 7;
            lrank[j] = atomicAdd(&cnt[bkt[j]], 1);
            atomicAdd(counts + key[j], 1);
        } else {
            bkt[j] = -1;
        }
    }
    __syncthreads();
    if (t < nbkt) {
        base[t] = (cnt[t] > 0) ? atomicAdd(&gcursor[t], cnt[t]) : 0;
    }
    __syncthreads();
#pragma unroll
    for (int j = 0; j < 8; ++j) {
        if (bkt[j] >= 0) {
            staging[(size_t)bkt[j] * BCAP + base[bkt[j]] + lrank[j]] =
                make_uint2(pk[j], w2[j]);
        }
    }
}

__global__ __launch_bounds__(256) void bucket_b(const uint2* __restrict__ staging,
                                                const int* __restrict__ gcursor,
                                                const int* __restrict__ row_ptr,
                                                unsigned* __restrict__ epack) {
    __shared__ int cnt2[512];
    const int b = blockIdx.x;
    const int t = threadIdx.x;
    cnt2[t] = 0;
    cnt2[t + 256] = 0;
    __syncthreads();
    const int cb = gcursor[b];
    for (int i = t; i < cb; i += 256) {
        const uint2 en = staging[(size_t)b * BCAP + i];
        const int key = (int)(en.y & 0x3ffff);
        const int lk = (int)(en.y >> 18);
        const int rank = atomicAdd(&cnt2[lk], 1);
        epack[row_ptr[key] + rank] = en.x;
    }
}

// ---------------- scans for row_ptr ----------------
__global__ __launch_bounds__(SCAN_T) void scan1_kern(int* __restrict__ data,
                                                     int* __restrict__ bsum, int n) {
    __shared__ int sh[SCAN_T];
    const int t = threadIdx.x;
    const int base = blockIdx.x * SCAN_ELEMS + t * 4;
    int v[4];
    int tsum = 0;
#pragma unroll
    for (int j = 0; j < 4; ++j) {
        v[j] = (base + j < n) ? data[base + j] : 0;
        tsum += v[j];
    }
    sh[t] = tsum;
    __syncthreads();
    for (int off = 1; off < SCAN_T; off <<= 1) {
        int x = (t >= off) ? sh[t - off] : 0;
        __syncthreads();
        sh[t] += x;
        __syncthreads();
    }
    if (t == SCAN_T - 1) bsum[blockIdx.x] = sh[t];
    int run = sh[t] - tsum;
#pragma unroll
    for (int j = 0; j < 4; ++j) {
        if (base + j < n) data[base + j] = run;
        run += v[j];
    }
}

__global__ __launch_bounds__(SCAN_T) void scan2_kern(int* __restrict__ bsum, int nb) {
    __shared__ int sh[SCAN_T];
    const int t = threadIdx.x;
    int val = (t < nb) ? bsum[t] : 0;
    sh[t] = val;
    __syncthreads();
    for (int off = 1; off < SCAN_T; off <<= 1) {
        int x = (t >= off) ? sh[t - off] : 0;
        __syncthreads();
        sh[t] += x;
        __syncthreads();
    }
    if (t < nb) bsum[t] = sh[t] - val;
}

__global__ __launch_bounds__(256) void scan3_kern(int* __restrict__ row_ptr,
                                                  const int* __restrict__ bsum,
                                                  int n, int total) {
    int i = blockIdx.x * blockDim.x + threadIdx.x;
    if (i < n) {
        row_ptr[i] = row_ptr[i] + bsum[i >> 10];
    } else if (i == n) {
        row_ptr[n] = total;
    }
}

// ---------------- Gather-aggregate: 2 edges per wave, 16 B/lane ----------------
__global__ __launch_bounds__(256) void aggregate_g(const unsigned short* __restrict__ xb,
                                                   const int* __restrict__ row_ptr,
                                                   const unsigned* __restrict__ epack,
                                                   unsigned short* __restrict__ Y,
                                                   int Nn) {
    const int d = blockIdx.x;
    const int r = threadIdx.x >> 6;
    if (d >= Nn) return;
    const int lane = threadIdx.x & 63;
    const int half = lane >> 5;
    const int f8 = (lane & 31) * 8;

    const int key = r * Nn + d;
    int e = row_ptr[key];
    const int end = row_ptr[key + 1];

    float acc[8] = {0.f, 0.f, 0.f, 0.f, 0.f, 0.f, 0.f, 0.f};

    for (; e + 8 <= end; e += 8) {
        unsigned p0 = epack[e + 0 + half];
        unsigned p1 = epack[e + 2 + half];
        unsigned p2 = epack[e + 4 + half];
        unsigned p3 = epack[e + 6 + half];
        bf16x8 h0 = *(const bf16x8*)(xb + (size_t)(p0 & 0xffff) * F + f8);
        bf16x8 h1 = *(const bf16x8*)(xb + (size_t)(p1 & 0xffff) * F + f8);
        bf16x8 h2 = *(const bf16x8*)(xb + (size_t)(p2 & 0xffff) * F + f8);
        bf16x8 h3 = *(const bf16x8*)(xb + (size_t)(p3 & 0xffff) * F + f8);
        const float v0 = ep_val(p0), v1 = ep_val(p1);
        const float v2 = ep_val(p2), v3 = ep_val(p3);
#pragma unroll
        for (int j = 0; j < 8; ++j) acc[j] = fmaf(bf2f((unsigned short)h0[j]), v0, acc[j]);
#pragma unroll
        for (int j = 0; j < 8; ++j) acc[j] = fmaf(bf2f((unsigned short)h1[j]), v1, acc[j]);
#pragma unroll
        for (int j = 0; j < 8; ++j) acc[j] = fmaf(bf2f((unsigned short)h2[j]), v2, acc[j]);
#pragma unroll
        for (int j = 0; j < 8; ++j) acc[j] = fmaf(bf2f((unsigned short)h3[j]), v3, acc[j]);
    }
    for (; e + 2 <= end; e += 2) {
        unsigned p = epack[e + half];
        const float v = ep_val(p);
        bf16x8 h = *(const bf16x8*)(xb + (size_t)(p & 0xffff) * F + f8);
#pragma unroll
        for (int j = 0; j < 8; ++j) acc[j] = fmaf(bf2f((unsigned short)h[j]), v, acc[j]);
    }
    if (e < end) {
        unsigned p = epack[e];
        const float v = half == 0 ? ep_val(p) : 0.f;
        bf16x8 h = *(const bf16x8*)(xb + (size_t)(p & 0xffff) * F + f8);
#pragma unroll
        for (int j = 0; j < 8; ++j) acc[j] = fmaf(bf2f((unsigned short)h[j]), v, acc[j]);
    }

#pragma unroll
    for (int j = 0; j < 8; ++j) acc[j] += __shfl_xor(acc[j], 32);

    if (half == 0) {
        bf16x8 o;
#pragma unroll
        for (int j = 0; j < 8; ++j) o[j] = (short)f2bf(acc[j]);
        *(bf16x8*)(Y + (size_t)d * KC + r * F + f8) = o;
    }
}

// ---------------- LDS-staged MFMA GEMM, BN=256, 2-phase dbuf, bf16 skip --------
// C = Y[Mp,1024] @ WT^T;  512 thr, 8 waves (2x4), per-wave 64x64 output.
// LAYER1: x1b = bf16(relu(C+b)) only.  LAYER2: out = relu(C+b) + bf2f(x1b).
template <bool LAYER2>
__global__ __launch_bounds__(512) void gemm_fused(const unsigned short* __restrict__ A,
                                                  const unsigned short* __restrict__ WT,
                                                  const float* __restrict__ bias,
                                                  float* __restrict__ out,
                                                  unsigned short* __restrict__ x1b,
                                                  int Nn, int nwg) {
    __shared__ unsigned short As[2][BM][BK];   // 2 x 8 KB
    __shared__ unsigned short Bs[2][BN][BK];   // 2 x 16 KB

    // bijective XCD swizzle (m204)
    const int xcd = blockIdx.x % 8;
    const int j = blockIdx.x / 8;
    const int q = nwg / 8, rr = nwg % 8;
    const int rb = (xcd < rr ? xcd * (q + 1) : rr * (q + 1) + (xcd - rr) * q) + j;
    const int row0 = rb * BM;

    const int tid = threadIdx.x;
    const int wave = tid >> 6, lane = tid & 63;
    const int wr = wave >> 2, wc = wave & 3;     // 2 x 4 wave grid, 64x64 each

    const int lrow = lane & 15, lk8 = (lane >> 4) * 8;

    const int srow = tid >> 2;          // 0..127
    const int scol = (tid & 3) * 8;

    f32x4 acc[4][4] = {};

#define STAGE(buf, k0)                                                               \
    {                                                                                \
        const unsigned short* gA = A + (size_t)(row0 + srow) * KC + (k0) + scol;     \
        __builtin_amdgcn_global_load_lds((glb_u32p)gA,                               \
            (lds_u32p)&As[buf][wave * 16][0], 16, 0, 0);                             \
        const unsigned short* gB0 = WT + (size_t)srow * KC + (k0) + scol;            \
        __builtin_amdgcn_global_load_lds((glb_u32p)gB0,                              \
            (lds_u32p)&Bs[buf][wave * 16][0], 16, 0, 0);                             \
        const unsigned short* gB1 = WT + (size_t)(128 + srow) * KC + (k0) + scol;    \
        __builtin_amdgcn_global_load_lds((glb_u32p)gB1,                              \
            (lds_u32p)&Bs[buf][128 + wave * 16][0], 16, 0, 0);                       \
    }

#define COMPUTE(buf)                                                                 \
    {                                                                                \
        bf16x8 a[4], b[4];                                                           \
        _Pragma("unroll")                                                            \
        for (int m = 0; m < 4; ++m)                                                  \
            a[m] = *(const bf16x8*)&As[buf][wr * 64 + m * 16 + lrow][lk8];           \
        _Pragma("unroll")                                                            \
        for (int n = 0; n < 4; ++n)                                                  \
            b[n] = *(const bf16x8*)&Bs[buf][wc * 64 + n * 16 + lrow][lk8];           \
        _Pragma("unroll")                                                            \
        for (int m = 0; m < 4; ++m)                                                  \
            _Pragma("unroll")                                                        \
            for (int n = 0; n < 4; ++n)                                              \
                acc[m][n] = __builtin_amdgcn_mfma_f32_16x16x32_bf16(a[m], b[n],      \
                                                                   acc[m][n], 0, 0, 0); \
    }

    STAGE(0, 0)
    __syncthreads();
    int cur = 0;
#pragma unroll 2
    for (int t = 0; t < NT - 1; ++t) {
        STAGE(cur ^ 1, (t + 1) * BK)
        COMPUTE(cur)
        __syncthreads();
        cur ^= 1;
    }
    COMPUTE(cur)
#undef STAGE
#undef COMPUTE

    // C/D layout: col = lane&15, row = (lane>>4)*4 + q  [m89/m91]
    const int crow = (lane >> 4) * 4;
    const int ccol = lane & 15;
#pragma unroll
    for (int m = 0; m < 4; ++m) {
#pragma unroll
        for (int q4 = 0; q4 < 4; ++q4) {
            const int grow = row0 + wr * 64 + m * 16 + crow + q4;
            if (grow >= Nn) continue;
#pragma unroll
            for (int n = 0; n < 4; ++n) {
                const int gcol = wc * 64 + n * 16 + ccol;
                float v = acc[m][n][q4] + bias[gcol];
                v = fmaxf(v, 0.f);
                const size_t oi = (size_t)grow * F + gcol;
                if (LAYER2) {
                    out[oi] = v + bf2f(x1b[oi]);   // bf16 skip path
                } else {
                    x1b[oi] = f2bf(v);             // x1 stored bf16 only
                }
            }
        }
    }
}

extern "C" void kernel_launch(void* const* d_in, const int* in_sizes, int n_in,
                              void* d_out, int out_size, void* d_ws, size_t ws_size,
                              hipStream_t stream) {
    const float* x    = (const float*)d_in[0];
    const int*   esrc = (const int*)  d_in[1];
    const int*   edst = (const int*)  d_in[2];
    const float* eval = (const float*)d_in[3];
    const float* W1   = (const float*)d_in[4];
    const float* b1   = (const float*)d_in[5];
    const float* W2   = (const float*)d_in[6];
    const float* b2   = (const float*)d_in[7];
    float* out = (float*)d_out;

    const int N = in_sizes[0] / F;
    const int R = in_sizes[4] / (F * F);
    const int E = in_sizes[1] / R;
    const int RE = R * E;
    const int RN = R * N;
    const int nrb = (N + BM - 1) / BM;         // 391 for N=50000
    const int Mp = nrb * BM;
    const int nwg = nrb;                       // BN=256 covers all cols
    const int nbkt = (N + 127) >> 7;           // 391 dst-buckets

    // ---- workspace layout ----
    char* ws = (char*)d_ws;
    unsigned short* Y = (unsigned short*)ws;             // [Mp][1024] bf16
    ws += (size_t)Mp * KC * sizeof(unsigned short);
    unsigned short* xb = (unsigned short*)ws;            // [N][256] bf16
    ws += (size_t)N * F * sizeof(unsigned short);
    unsigned short* x1b = (unsigned short*)ws;           // [N][256] bf16
    ws += (size_t)N * F * sizeof(unsigned short);
    unsigned short* WTc1 = (unsigned short*)ws;          // [256][1024] bf16
    ws += (size_t)F * KC * sizeof(unsigned short);
    unsigned short* WTc2 = (unsigned short*)ws;
    ws += (size_t)F * KC * sizeof(unsigned short);
    unsigned* epack = (unsigned*)ws;                     // [R*E] 4B packed
    ws += (size_t)RE * sizeof(unsigned);
    int* row_ptr = (int*)ws;                             // [R*N + 1]
    ws += (size_t)(RN + 1) * sizeof(int);
    int* gcursor = (int*)ws;                             // [nbkt]
    ws += (size_t)nbkt * sizeof(int);
    int* bsum = (int*)ws;                                // [<=256]
    ws += 256 * sizeof(int);
    uint2* staging = (uint2*)ws;                         // [nbkt*BCAP]
    ws += (size_t)nbkt * BCAP * sizeof(uint2);

    // ---- CSR build ----
    hipMemsetAsync(row_ptr, 0, ((size_t)(RN + 1) + nbkt) * sizeof(int), stream);
    {
        const int ablocks = (RE + ACHUNK - 1) / ACHUNK;
        bucket_a<<<ablocks, 512, 0, stream>>>(esrc, edst, eval, row_ptr, gcursor,
                                              staging, RE, E, N, nbkt);
    }
    const int nb_scan = (RN + SCAN_ELEMS - 1) / SCAN_ELEMS;
    scan1_kern<<<nb_scan, SCAN_T, 0, stream>>>(row_ptr, bsum, RN);
    scan2_kern<<<1, SCAN_T, 0, stream>>>(bsum, nb_scan);
    scan3_kern<<<(RN + 1 + 255) / 256, 256, 0, stream>>>(row_ptr, bsum, RN, RE);
    bucket_b<<<nbkt, 256, 0, stream>>>(staging, gcursor, row_ptr, epack);

    // ---- weight transpose+convert ----
    dim3 tgrid(F / 32, F / 32, 2 * R);
    transpose_wcat2<<<tgrid, 256, 0, stream>>>(W1, W2, WTc1, WTc2, R);

    // ---- input conversion ----
    convert_bf16<<<(N * (F / 8) + 255) / 256, 256, 0, stream>>>(x, xb, N * (F / 8));

    // layer 1: Y = gather(xb); x1b = bf16(relu(Y @ Wc1 + b1))
    aggregate_g<<<N, 256, 0, stream>>>(xb, row_ptr, epack, Y, N);
    gemm_fused<false><<<nwg, 512, 0, stream>>>(Y, WTc1, b1, out, x1b, N, nwg);

    // layer 2: Y = gather(x1b); out = relu(Y @ Wc2 + b2) + x1b
    aggregate_g<<<N, 256, 0, stream>>>(x1b, row_ptr, epack, Y, N);
    gemm_fused<true><<<nwg, 512, 0, stream>>>(Y, WTc2, b2, out, x1b, N, nwg);
}